// Round 2
// baseline (305.209 us; speedup 1.0000x reference)
//
#include <hip/hip_runtime.h>
#include <stdint.h>

typedef unsigned short ushort_t;
typedef __attribute__((__ext_vector_type__(8))) __bf16 bf16x8;
typedef __attribute__((__ext_vector_type__(4))) float f32x4;

__device__ inline ushort_t f2bf(float f) {
    unsigned int u = __float_as_uint(f);
    u = u + 0x7FFFu + ((u >> 16) & 1u);
    return (ushort_t)(u >> 16);
}
__device__ inline float bf2f(ushort_t h) {
    return __uint_as_float(((unsigned int)h) << 16);
}

#define GLOAD16(gp, lp) __builtin_amdgcn_global_load_lds( \
    (__attribute__((address_space(1))) void*)(gp),        \
    (__attribute__((address_space(3))) void*)(lp), 16, 0, 0)

// =====================================================================
// Generic NT GEMM: C[M,N] = A[M,K] * B[N,K]^T  (A,B bf16-as-ushort)
// BM=128 fixed, BN in {128,64}. 256 threads = 4 waves as 2x2,
// wave tile 64 x (BN/2). MFMA 16x16x32 bf16.
// MODE 0: C bf16 (+optional bias, scale)
// MODE 3: C f32 + bias (final output)
// MODE 4: fused QKV epilogue: gcol<512 -> Q, <1024 -> K, else V transposed.
//         Cv = base of [Q | K | Vt] (each 8388608 elems). bias = packed[1536].
// MODE 5: E = exp(v*scale) -> bf16 C, plus f32 row-sum atomicAdd to rowsum.
// Grid: (N/BN, M/128, Z). A,B,C advanced by z*sA/z*sB/z*sC elements.
// =====================================================================
template<int MODE, int BN>
__global__ __launch_bounds__(256)
void gemm_nt(const ushort_t* __restrict__ A, const ushort_t* __restrict__ B,
             void* __restrict__ Cv, const float* __restrict__ bias,
             int K, int lda, int ldb, int ldc, float scale,
             long long sA, long long sB, long long sC,
             float* __restrict__ rowsum)
{
    constexpr int WN = BN / 2;        // wave col extent
    constexpr int NR = WN / 16;       // col fragment repeats (4 or 2)
    __shared__ __align__(16) char lds[8192 + BN * 64];
    char* ldsA = lds;
    char* ldsB = lds + 8192;

    const int t = threadIdx.x;
    const int z = blockIdx.z;
    A += (size_t)z * (size_t)sA;
    B += (size_t)z * (size_t)sB;

    const int rowBase = blockIdx.y * 128;
    const int colBase = blockIdx.x * BN;

    const int w    = t >> 6;
    const int lane = t & 63;
    const int wr = w >> 1, wc = w & 1;
    const int lr = lane & 15, lg = lane >> 4;

    f32x4 acc[4][NR];
#pragma unroll
    for (int i = 0; i < 4; ++i)
#pragma unroll
        for (int j = 0; j < NR; ++j)
            acc[i][j] = (f32x4){0.f, 0.f, 0.f, 0.f};

    for (int kt = 0; kt < K; kt += 32) {
#pragma unroll
        for (int i = 0; i < 2; ++i) {              // A: 128 rows x 4 granules
            const int L = i * 256 + t;
            const int row = L >> 2, g = L & 3;
            GLOAD16(A + (size_t)(rowBase + row) * (size_t)lda + (kt + g * 8),
                    ldsA + L * 16);
        }
#pragma unroll
        for (int i = 0; i < BN / 64; ++i) {        // B: BN rows x 4 granules
            const int L = i * 256 + t;
            const int row = L >> 2, g = L & 3;
            GLOAD16(B + (size_t)(colBase + row) * (size_t)ldb + (kt + g * 8),
                    ldsB + L * 16);
        }
        __syncthreads();

        const bf16x8* A8 = (const bf16x8*)ldsA;
        const bf16x8* B8 = (const bf16x8*)ldsB;
        bf16x8 af[4], bq[NR];
#pragma unroll
        for (int mi = 0; mi < 4; ++mi)
            af[mi] = A8[(wr * 64 + mi * 16 + lr) * 4 + lg];
#pragma unroll
        for (int ni = 0; ni < NR; ++ni)
            bq[ni] = B8[(wc * WN + ni * 16 + lr) * 4 + lg];
#pragma unroll
        for (int mi = 0; mi < 4; ++mi)
#pragma unroll
            for (int ni = 0; ni < NR; ++ni)
                acc[mi][ni] = __builtin_amdgcn_mfma_f32_16x16x32_bf16(
                    af[mi], bq[ni], acc[mi][ni], 0, 0, 0);
        __syncthreads();
    }

    // ---- epilogue ----
    float rs[4][4];
    if (MODE == 5) {
#pragma unroll
        for (int mi = 0; mi < 4; ++mi)
#pragma unroll
            for (int r = 0; r < 4; ++r) rs[mi][r] = 0.f;
    }

#pragma unroll
    for (int mi = 0; mi < 4; ++mi) {
#pragma unroll
        for (int ni = 0; ni < NR; ++ni) {
#pragma unroll
            for (int r = 0; r < 4; ++r) {
                const int grow = rowBase + wr * 64 + mi * 16 + lg * 4 + r;
                const int gcol = colBase + wc * WN + ni * 16 + lr;
                float v = acc[mi][ni][r] * scale;
                if (MODE == 0) {
                    if (bias) v += bias[gcol];
                    ushort_t* C = (ushort_t*)Cv + (size_t)z * (size_t)sC;
                    C[(size_t)grow * (size_t)ldc + gcol] = f2bf(v);
                } else if (MODE == 3) {
                    float* C = (float*)Cv + (size_t)z * (size_t)sC;
                    C[(size_t)grow * (size_t)ldc + gcol] = v + bias[gcol];
                } else if (MODE == 4) {
                    v += bias[gcol];
                    ushort_t* C = (ushort_t*)Cv;
                    const int seg = gcol >> 9, c = gcol & 511;
                    if (seg == 0) {
                        C[(size_t)grow * 512 + c] = f2bf(v);
                    } else if (seg == 1) {
                        C[8388608 + (size_t)grow * 512 + c] = f2bf(v);
                    } else {
                        const int b = grow >> 11, n = grow & 2047;
                        C[16777216 + (size_t)b * 1048576 + (size_t)c * 2048 + n] = f2bf(v);
                    }
                } else { // MODE 5
                    float e = __expf(v);
                    ushort_t* C = (ushort_t*)Cv + (size_t)z * (size_t)sC;
                    C[(size_t)grow * (size_t)ldc + gcol] = f2bf(e);
                    rs[mi][r] += e;
                }
            }
        }
    }

    if (MODE == 5) {
#pragma unroll
        for (int mi = 0; mi < 4; ++mi) {
#pragma unroll
            for (int r = 0; r < 4; ++r) {
                float s = rs[mi][r];
                s += __shfl_xor(s, 1);
                s += __shfl_xor(s, 2);
                s += __shfl_xor(s, 4);
                s += __shfl_xor(s, 8);
                if (lr == 0) {
                    const int grow = rowBase + wr * 64 + mi * 16 + lg * 4 + r;
                    atomicAdd(&rowsum[z * 2048 + grow], s);
                }
            }
        }
    }
}

// =====================================================================
__global__ __launch_bounds__(256)
void cvt_bf16(const float* __restrict__ src, ushort_t* __restrict__ dst, int n4)
{
    int i = blockIdx.x * 256 + threadIdx.x;
    if (i >= n4) return;
    float4 v = ((const float4*)src)[i];
    union { ushort_t h[4]; uint2 u; } p;
    p.h[0] = f2bf(v.x); p.h[1] = f2bf(v.y); p.h[2] = f2bf(v.z); p.h[3] = f2bf(v.w);
    ((uint2*)dst)[i] = p.u;
}

__global__ __launch_bounds__(256)
void pack_bias(const float* __restrict__ q, const float* __restrict__ k,
               const float* __restrict__ v, float* __restrict__ dst)
{
    int i = blockIdx.x * 256 + threadIdx.x;   // 0..1535
    if (i < 512) dst[i] = q[i];
    else if (i < 1024) dst[i] = k[i - 512];
    else if (i < 1536) dst[i] = v[i - 1024];
}

__global__ __launch_bounds__(256)
void zero_f32(float* __restrict__ p, int n)
{
    int i = blockIdx.x * 256 + threadIdx.x;
    if (i < n) p[i] = 0.f;
}

// =====================================================================
// attn = E * (1/rowsum) + intensity, bf16 in-place over E. 1 block per row.
// =====================================================================
__global__ __launch_bounds__(256)
void norm_add(ushort_t* __restrict__ E, const float* __restrict__ rowsum,
              const float* __restrict__ inten)
{
    const int R = blockIdx.x;            // 0..16383
    const int t = threadIdx.x;
    const float inv = 1.f / rowsum[R];
    ushort_t* erow = E + (size_t)R * 2048;
    const float* irow = inten + (size_t)R * 2048;

    union { ushort_t h[8]; uint4 u; } p;
    p.u = *(const uint4*)(erow + t * 8);
    float4 i0 = *(const float4*)(irow + t * 8);
    float4 i1 = *(const float4*)(irow + t * 8 + 4);
    float o[8] = {
        bf2f(p.h[0]) * inv + i0.x, bf2f(p.h[1]) * inv + i0.y,
        bf2f(p.h[2]) * inv + i0.z, bf2f(p.h[3]) * inv + i0.w,
        bf2f(p.h[4]) * inv + i1.x, bf2f(p.h[5]) * inv + i1.y,
        bf2f(p.h[6]) * inv + i1.z, bf2f(p.h[7]) * inv + i1.w };
#pragma unroll
    for (int j = 0; j < 8; ++j) p.h[j] = f2bf(o[j]);
    *(uint4*)(erow + t * 8) = p.u;
}

// =====================================================================
extern "C" void kernel_launch(void* const* d_in, const int* in_sizes, int n_in,
                              void* d_out, int out_size, void* d_ws, size_t ws_size,
                              hipStream_t stream)
{
    const float* X    = (const float*)d_in[0];
    const float* inten= (const float*)d_in[1];
    const float* WQw  = (const float*)d_in[2];
    const float* WQb  = (const float*)d_in[3];
    const float* WKw  = (const float*)d_in[4];
    const float* WKb  = (const float*)d_in[5];
    const float* WVw  = (const float*)d_in[6];
    const float* WVb  = (const float*)d_in[7];
    const float* Wow  = (const float*)d_in[8];
    const float* Wob  = (const float*)d_in[9];
    float* out = (float*)d_out;

    char* ws = (char*)d_ws;
    ushort_t* Xb    = (ushort_t*)(ws + 0);           // 16 MiB
    ushort_t* Wqkv  = (ushort_t*)(ws + 16777216);    // 1536x512 bf16 = 1.5 MiB
    ushort_t* Wob2  = (ushort_t*)(ws + 18350080);    // 512x512 bf16 = 0.5 MiB
    float*    biasP = (float*)   (ws + 18874368);    // 1536 f32
    float*    rowsum= (float*)   (ws + 18880512);    // 16384 f32
    ushort_t* QKV   = (ushort_t*)(ws + 19922944);    // Q|K|Vt, 3x16 MiB
    ushort_t* out1  = (ushort_t*)(ws + 70254592);    // 16 MiB
    ushort_t* Sbf   = (ushort_t*)(ws + 87031808);    // 8x2048x2048 bf16 = 64 MiB
    ushort_t* Qb = QKV;
    ushort_t* Kb = QKV + 8388608;
    ushort_t* Vt = QKV + 16777216;

    const float scale = 0.044194173824159216f;       // 1/sqrt(512)

    cvt_bf16<<<dim3(8192), dim3(256), 0, stream>>>(X,   Xb, 2097152);
    cvt_bf16<<<dim3(256),  dim3(256), 0, stream>>>(WQw, Wqkv,           65536);
    cvt_bf16<<<dim3(256),  dim3(256), 0, stream>>>(WKw, Wqkv + 262144,  65536);
    cvt_bf16<<<dim3(256),  dim3(256), 0, stream>>>(WVw, Wqkv + 524288,  65536);
    cvt_bf16<<<dim3(256),  dim3(256), 0, stream>>>(Wow, Wob2,           65536);
    pack_bias<<<dim3(6),  dim3(256), 0, stream>>>(WQb, WKb, WVb, biasP);
    zero_f32<<<dim3(64),  dim3(256), 0, stream>>>(rowsum, 16384);

    // fused QKV projection: [16384,512] @ [1536,512]^T
    gemm_nt<4, 128><<<dim3(12, 128, 1), dim3(256), 0, stream>>>(
        Xb, Wqkv, QKV, biasP, 512, 512, 512, 0, 1.f, 0, 0, 0, nullptr);

    // E = exp(scale * Q K^T) bf16 + row sums, per batch
    gemm_nt<5, 128><<<dim3(16, 16, 8), dim3(256), 0, stream>>>(
        Qb, Kb, Sbf, nullptr, 512, 512, 512, 2048, scale,
        2048LL * 512, 2048LL * 512, 2048LL * 2048, rowsum);

    // attn = E/rowsum + intensity (bf16, in place)
    norm_add<<<dim3(16384), dim3(256), 0, stream>>>(Sbf, rowsum, inten);

    // out1 = attn @ Vt^T per batch  [2048,512] bf16
    gemm_nt<0, 64><<<dim3(8, 16, 8), dim3(256), 0, stream>>>(
        Sbf, Vt, out1, nullptr, 2048, 2048, 2048, 512, 1.f,
        2048LL * 2048, 512LL * 2048, 2048LL * 512, nullptr);

    // out = out1 @ Wo^T + bo  [16384,512] f32
    gemm_nt<3, 64><<<dim3(8, 128, 1), dim3(256), 0, stream>>>(
        out1, Wob2, out, Wob, 512, 512, 512, 512, 1.f, 0, 0, 0, nullptr);
}

// Round 3
// 265.815 us; speedup vs baseline: 1.1482x; 1.1482x over previous
//
#include <hip/hip_runtime.h>
#include <stdint.h>

typedef unsigned short ushort_t;
typedef __attribute__((__ext_vector_type__(8))) __bf16 bf16x8;
typedef __attribute__((__ext_vector_type__(4))) float f32x4;

__device__ inline ushort_t f2bf(float f) {
    unsigned int u = __float_as_uint(f);
    u = u + 0x7FFFu + ((u >> 16) & 1u);
    return (ushort_t)(u >> 16);
}
__device__ inline float bf2f(ushort_t h) {
    return __uint_as_float(((unsigned int)h) << 16);
}

#define GLOAD16(gp, lp) __builtin_amdgcn_global_load_lds( \
    (__attribute__((address_space(1))) void*)(gp),        \
    (__attribute__((address_space(3))) void*)(lp), 16, 0, 0)

// =====================================================================
// Generic NT GEMM: C[M,N] = A[M,K] * B[N,K]^T  (A,B bf16-as-ushort)
// BM=128, BN in {128,64}, BK in {32,64}. 256 thr = 4 waves (2x2),
// wave tile 64 x (BN/2). MFMA 16x16x32 bf16.
// XCD-chunked block swizzle: hardware block h -> logical (h%8)*(nwg/8)+h/8
// so each XCD gets a contiguous chunk of logical blocks (L2 locality).
// MODE 0: C bf16 (+optional bias, scale)
// MODE 3: C f32 + bias (final output)
// MODE 4: fused QKV epilogue: col<512 -> Q, <1024 -> K, else V transposed.
// MODE 5: C = exp(v*scale) -> bf16 (row sums computed later in norm_add)
// =====================================================================
template<int MODE, int BN, int BK>
__global__ __launch_bounds__(256)
void gemm_nt(const ushort_t* __restrict__ A, const ushort_t* __restrict__ B,
             void* __restrict__ Cv, const float* __restrict__ bias,
             int K, int lda, int ldb, int ldc, float scale,
             long long sA, long long sB, long long sC)
{
    constexpr int WN  = BN / 2;          // wave col extent
    constexpr int NR  = WN / 16;         // col fragment repeats
    constexpr int GPR = BK / 8;          // 16B granules per row
    constexpr int AG  = 128 * GPR;       // A granules per tile
    constexpr int BG  = BN * GPR;        // B granules per tile
    __shared__ __align__(16) char lds[(128 + BN) * BK * 2];
    char* ldsA = lds;
    char* ldsB = lds + 128 * BK * 2;

    const int t = threadIdx.x;

    // ---- XCD-chunked swizzle (all launch grids are multiples of 8) ----
    const int gx = gridDim.x, gy = gridDim.y;
    const int nwg = gx * gy * gridDim.z;
    int h = (blockIdx.z * gy + blockIdx.y) * gx + blockIdx.x;
    int logical = (h & 7) * (nwg >> 3) + (h >> 3);
    const int bx = logical % gx;
    const int tmp = logical / gx;
    const int by = tmp % gy;
    const int z  = tmp / gy;

    A += (size_t)z * (size_t)sA;
    B += (size_t)z * (size_t)sB;

    const int rowBase = by * 128;
    const int colBase = bx * BN;

    const int w    = t >> 6;
    const int lane = t & 63;
    const int wr = w >> 1, wc = w & 1;
    const int lr = lane & 15, lg = lane >> 4;

    f32x4 acc[4][NR];
#pragma unroll
    for (int i = 0; i < 4; ++i)
#pragma unroll
        for (int j = 0; j < NR; ++j)
            acc[i][j] = (f32x4){0.f, 0.f, 0.f, 0.f};

    for (int kt = 0; kt < K; kt += BK) {
#pragma unroll
        for (int i = 0; i < AG / 256; ++i) {
            const int L = i * 256 + t;
            const int row = L / GPR, g = L % GPR;
            GLOAD16(A + (size_t)(rowBase + row) * (size_t)lda + (kt + g * 8),
                    ldsA + L * 16);
        }
#pragma unroll
        for (int i = 0; i < BG / 256; ++i) {
            const int L = i * 256 + t;
            const int row = L / GPR, g = L % GPR;
            GLOAD16(B + (size_t)(colBase + row) * (size_t)ldb + (kt + g * 8),
                    ldsB + L * 16);
        }
        __syncthreads();

        const bf16x8* A8 = (const bf16x8*)ldsA;
        const bf16x8* B8 = (const bf16x8*)ldsB;
#pragma unroll
        for (int kk = 0; kk < BK / 32; ++kk) {
            bf16x8 af[4], bq[NR];
#pragma unroll
            for (int mi = 0; mi < 4; ++mi)
                af[mi] = A8[(wr * 64 + mi * 16 + lr) * GPR + kk * 4 + lg];
#pragma unroll
            for (int ni = 0; ni < NR; ++ni)
                bq[ni] = B8[(wc * WN + ni * 16 + lr) * GPR + kk * 4 + lg];
#pragma unroll
            for (int mi = 0; mi < 4; ++mi)
#pragma unroll
                for (int ni = 0; ni < NR; ++ni)
                    acc[mi][ni] = __builtin_amdgcn_mfma_f32_16x16x32_bf16(
                        af[mi], bq[ni], acc[mi][ni], 0, 0, 0);
        }
        __syncthreads();
    }

    // ---- epilogue ----
#pragma unroll
    for (int mi = 0; mi < 4; ++mi) {
#pragma unroll
        for (int ni = 0; ni < NR; ++ni) {
#pragma unroll
            for (int r = 0; r < 4; ++r) {
                const int grow = rowBase + wr * 64 + mi * 16 + lg * 4 + r;
                const int gcol = colBase + wc * WN + ni * 16 + lr;
                float v = acc[mi][ni][r] * scale;
                if (MODE == 0) {
                    if (bias) v += bias[gcol];
                    ushort_t* C = (ushort_t*)Cv + (size_t)z * (size_t)sC;
                    C[(size_t)grow * (size_t)ldc + gcol] = f2bf(v);
                } else if (MODE == 3) {
                    float* C = (float*)Cv;
                    C[(size_t)grow * (size_t)ldc + gcol] = v + bias[gcol];
                } else if (MODE == 4) {
                    v += bias[gcol];
                    ushort_t* C = (ushort_t*)Cv;
                    const int seg = gcol >> 9, c = gcol & 511;
                    if (seg == 0) {
                        C[(size_t)grow * 512 + c] = f2bf(v);
                    } else if (seg == 1) {
                        C[8388608 + (size_t)grow * 512 + c] = f2bf(v);
                    } else {
                        const int b = grow >> 11, n = grow & 2047;
                        C[16777216 + (size_t)b * 1048576 + (size_t)c * 2048 + n] = f2bf(v);
                    }
                } else { // MODE 5: E = exp(score)
                    ushort_t* C = (ushort_t*)Cv + (size_t)z * (size_t)sC;
                    C[(size_t)grow * (size_t)ldc + gcol] = f2bf(__expf(v));
                }
            }
        }
    }
}

// =====================================================================
__global__ __launch_bounds__(256)
void cvt_bf16(const float* __restrict__ src, ushort_t* __restrict__ dst, int n4)
{
    int i = blockIdx.x * 256 + threadIdx.x;
    if (i >= n4) return;
    float4 v = ((const float4*)src)[i];
    union { ushort_t h[4]; uint2 u; } p;
    p.h[0] = f2bf(v.x); p.h[1] = f2bf(v.y); p.h[2] = f2bf(v.z); p.h[3] = f2bf(v.w);
    ((uint2*)dst)[i] = p.u;
}

__global__ __launch_bounds__(256)
void pack_bias(const float* __restrict__ q, const float* __restrict__ k,
               const float* __restrict__ v, float* __restrict__ dst)
{
    int i = blockIdx.x * 256 + threadIdx.x;   // 0..1535
    if (i < 512) dst[i] = q[i];
    else if (i < 1024) dst[i] = k[i - 512];
    else if (i < 1536) dst[i] = v[i - 1024];
}

// =====================================================================
// attn = E/rowsum + intensity, bf16 in-place over E. One block per row;
// the block computes the row sum itself (no atomics needed).
// =====================================================================
__global__ __launch_bounds__(256)
void norm_add(ushort_t* __restrict__ E, const float* __restrict__ inten)
{
    const int R = blockIdx.x;            // 0..16383
    const int t = threadIdx.x;
    const int w = t >> 6, lane = t & 63;
    ushort_t* erow = E + (size_t)R * 2048;
    const float* irow = inten + (size_t)R * 2048;

    union { ushort_t h[8]; uint4 u; } p;
    p.u = *(const uint4*)(erow + t * 8);
    float f[8];
#pragma unroll
    for (int j = 0; j < 8; ++j) f[j] = bf2f(p.h[j]);

    float s = 0.f;
#pragma unroll
    for (int j = 0; j < 8; ++j) s += f[j];
#pragma unroll
    for (int off = 32; off > 0; off >>= 1) s += __shfl_xor(s, off);

    __shared__ float red[4];
    if (lane == 0) red[w] = s;
    __syncthreads();
    const float inv = 1.f / (red[0] + red[1] + red[2] + red[3]);

    float4 i0 = *(const float4*)(irow + t * 8);
    float4 i1 = *(const float4*)(irow + t * 8 + 4);
    float o[8] = { f[0]*inv + i0.x, f[1]*inv + i0.y, f[2]*inv + i0.z, f[3]*inv + i0.w,
                   f[4]*inv + i1.x, f[5]*inv + i1.y, f[6]*inv + i1.z, f[7]*inv + i1.w };
#pragma unroll
    for (int j = 0; j < 8; ++j) p.h[j] = f2bf(o[j]);
    *(uint4*)(erow + t * 8) = p.u;
}

// =====================================================================
extern "C" void kernel_launch(void* const* d_in, const int* in_sizes, int n_in,
                              void* d_out, int out_size, void* d_ws, size_t ws_size,
                              hipStream_t stream)
{
    const float* X    = (const float*)d_in[0];
    const float* inten= (const float*)d_in[1];
    const float* WQw  = (const float*)d_in[2];
    const float* WQb  = (const float*)d_in[3];
    const float* WKw  = (const float*)d_in[4];
    const float* WKb  = (const float*)d_in[5];
    const float* WVw  = (const float*)d_in[6];
    const float* WVb  = (const float*)d_in[7];
    const float* Wow  = (const float*)d_in[8];
    const float* Wob  = (const float*)d_in[9];
    float* out = (float*)d_out;

    char* ws = (char*)d_ws;
    ushort_t* Xb    = (ushort_t*)(ws + 0);           // 16 MiB
    ushort_t* Wqkv  = (ushort_t*)(ws + 16777216);    // 1536x512 bf16
    ushort_t* Wob2  = (ushort_t*)(ws + 18350080);    // 512x512 bf16
    float*    biasP = (float*)   (ws + 18874368);    // 1536 f32
    ushort_t* QKV   = (ushort_t*)(ws + 19922944);    // Q|K|Vt, 3x16 MiB
    ushort_t* out1  = (ushort_t*)(ws + 70254592);    // 16 MiB
    ushort_t* Sbf   = (ushort_t*)(ws + 87031808);    // 8x2048x2048 bf16 = 64 MiB
    ushort_t* Qb = QKV;
    ushort_t* Kb = QKV + 8388608;
    ushort_t* Vt = QKV + 16777216;

    const float scale = 0.044194173824159216f;       // 1/sqrt(512)

    cvt_bf16<<<dim3(8192), dim3(256), 0, stream>>>(X,   Xb, 2097152);
    cvt_bf16<<<dim3(256),  dim3(256), 0, stream>>>(WQw, Wqkv,           65536);
    cvt_bf16<<<dim3(256),  dim3(256), 0, stream>>>(WKw, Wqkv + 262144,  65536);
    cvt_bf16<<<dim3(256),  dim3(256), 0, stream>>>(WVw, Wqkv + 524288,  65536);
    cvt_bf16<<<dim3(256),  dim3(256), 0, stream>>>(Wow, Wob2,           65536);
    pack_bias<<<dim3(6),  dim3(256), 0, stream>>>(WQb, WKb, WVb, biasP);

    // fused QKV projection: [16384,512] @ [1536,512]^T
    gemm_nt<4, 128, 64><<<dim3(12, 128, 1), dim3(256), 0, stream>>>(
        Xb, Wqkv, QKV, biasP, 512, 512, 512, 0, 1.f, 0, 0, 0);

    // E = exp(scale * Q K^T) bf16, per batch
    gemm_nt<5, 128, 64><<<dim3(16, 16, 8), dim3(256), 0, stream>>>(
        Qb, Kb, Sbf, nullptr, 512, 512, 512, 2048, scale,
        2048LL * 512, 2048LL * 512, 2048LL * 2048);

    // attn = E/rowsum + intensity (bf16, in place)
    norm_add<<<dim3(16384), dim3(256), 0, stream>>>(Sbf, inten);

    // out1 = attn @ Vt^T per batch  [2048,512] bf16
    gemm_nt<0, 64, 64><<<dim3(8, 16, 8), dim3(256), 0, stream>>>(
        Sbf, Vt, out1, nullptr, 2048, 2048, 2048, 512, 1.f,
        2048LL * 2048, 512LL * 2048, 2048LL * 512);

    // out = out1 @ Wo^T + bo  [16384,512] f32
    gemm_nt<3, 64, 64><<<dim3(8, 128, 1), dim3(256), 0, stream>>>(
        out1, Wob2, out, Wob, 512, 512, 512, 512, 1.f, 0, 0, 0);
}

// Round 4
// 243.277 us; speedup vs baseline: 1.2546x; 1.0926x over previous
//
#include <hip/hip_runtime.h>
#include <stdint.h>

typedef unsigned short ushort_t;
typedef __attribute__((__ext_vector_type__(8))) __bf16 bf16x8;
typedef __attribute__((__ext_vector_type__(4))) float f32x4;

__device__ inline ushort_t f2bf(float f) {
    unsigned int u = __float_as_uint(f);
    u = u + 0x7FFFu + ((u >> 16) & 1u);
    return (ushort_t)(u >> 16);
}
__device__ inline float bf2f(ushort_t h) {
    return __uint_as_float(((unsigned int)h) << 16);
}

#define GLOAD16(gp, lp) __builtin_amdgcn_global_load_lds( \
    (__attribute__((address_space(1))) void*)(gp),        \
    (__attribute__((address_space(3))) void*)(lp), 16, 0, 0)

// =====================================================================
// Generic NT GEMM: C[M,N] = A[M,K] * B[N,K]^T  (A,B bf16-as-ushort)
// BM=128, BN in {128,64}, BK=32. 256 thr = 4 waves (2x2),
// wave tile 64 x (BN/2). MFMA 16x16x32 bf16.
// XCD-chunked block swizzle (grids are multiples of 8).
// MODE 0: C bf16 (+optional bias, scale)
// MODE 3: C f32 + bias (final output)
// MODE 4: fused QKV epilogue: three row-major [16384,512] outputs (Q|K|V)
// MODE 5: C = exp(v*scale) -> bf16 (row sums computed later in norm_add)
// =====================================================================
template<int MODE, int BN, int BK>
__global__ __launch_bounds__(256)
void gemm_nt(const ushort_t* __restrict__ A, const ushort_t* __restrict__ B,
             void* __restrict__ Cv, const float* __restrict__ bias,
             int K, int lda, int ldb, int ldc, float scale,
             long long sA, long long sB, long long sC)
{
    constexpr int WN  = BN / 2;          // wave col extent
    constexpr int NR  = WN / 16;         // col fragment repeats
    constexpr int GPR = BK / 8;          // 16B granules per row
    constexpr int AG  = 128 * GPR;       // A granules per tile
    constexpr int BG  = BN * GPR;        // B granules per tile
    __shared__ __align__(16) char lds[(128 + BN) * BK * 2];
    char* ldsA = lds;
    char* ldsB = lds + 128 * BK * 2;

    const int t = threadIdx.x;

    // ---- XCD-chunked swizzle ----
    const int gx = gridDim.x, gy = gridDim.y;
    const int nwg = gx * gy * gridDim.z;
    int h = (blockIdx.z * gy + blockIdx.y) * gx + blockIdx.x;
    int logical = (h & 7) * (nwg >> 3) + (h >> 3);
    const int bx = logical % gx;
    const int tmp = logical / gx;
    const int by = tmp % gy;
    const int z  = tmp / gy;

    A += (size_t)z * (size_t)sA;
    B += (size_t)z * (size_t)sB;

    const int rowBase = by * 128;
    const int colBase = bx * BN;

    const int w    = t >> 6;
    const int lane = t & 63;
    const int wr = w >> 1, wc = w & 1;
    const int lr = lane & 15, lg = lane >> 4;

    f32x4 acc[4][NR];
#pragma unroll
    for (int i = 0; i < 4; ++i)
#pragma unroll
        for (int j = 0; j < NR; ++j)
            acc[i][j] = (f32x4){0.f, 0.f, 0.f, 0.f};

    for (int kt = 0; kt < K; kt += BK) {
#pragma unroll
        for (int i = 0; i < AG / 256; ++i) {
            const int L = i * 256 + t;
            const int row = L / GPR, g = L % GPR;
            GLOAD16(A + (size_t)(rowBase + row) * (size_t)lda + (kt + g * 8),
                    ldsA + L * 16);
        }
#pragma unroll
        for (int i = 0; i < BG / 256; ++i) {
            const int L = i * 256 + t;
            const int row = L / GPR, g = L % GPR;
            GLOAD16(B + (size_t)(colBase + row) * (size_t)ldb + (kt + g * 8),
                    ldsB + L * 16);
        }
        __syncthreads();

        const bf16x8* A8 = (const bf16x8*)ldsA;
        const bf16x8* B8 = (const bf16x8*)ldsB;
#pragma unroll
        for (int kk = 0; kk < BK / 32; ++kk) {
            bf16x8 af[4], bq[NR];
#pragma unroll
            for (int mi = 0; mi < 4; ++mi)
                af[mi] = A8[(wr * 64 + mi * 16 + lr) * GPR + kk * 4 + lg];
#pragma unroll
            for (int ni = 0; ni < NR; ++ni)
                bq[ni] = B8[(wc * WN + ni * 16 + lr) * GPR + kk * 4 + lg];
#pragma unroll
            for (int mi = 0; mi < 4; ++mi)
#pragma unroll
                for (int ni = 0; ni < NR; ++ni)
                    acc[mi][ni] = __builtin_amdgcn_mfma_f32_16x16x32_bf16(
                        af[mi], bq[ni], acc[mi][ni], 0, 0, 0);
        }
        __syncthreads();
    }

    // ---- epilogue ----
#pragma unroll
    for (int mi = 0; mi < 4; ++mi) {
#pragma unroll
        for (int ni = 0; ni < NR; ++ni) {
#pragma unroll
            for (int r = 0; r < 4; ++r) {
                const int grow = rowBase + wr * 64 + mi * 16 + lg * 4 + r;
                const int gcol = colBase + wc * WN + ni * 16 + lr;
                float v = acc[mi][ni][r] * scale;
                if (MODE == 0) {
                    if (bias) v += bias[gcol];
                    ushort_t* C = (ushort_t*)Cv + (size_t)z * (size_t)sC;
                    C[(size_t)grow * (size_t)ldc + gcol] = f2bf(v);
                } else if (MODE == 3) {
                    float* C = (float*)Cv;
                    C[(size_t)grow * (size_t)ldc + gcol] = v + bias[gcol];
                } else if (MODE == 4) {
                    v += bias[gcol];
                    const int seg = gcol >> 9, c = gcol & 511;
                    ushort_t* C = (ushort_t*)Cv;
                    C[(size_t)seg * 8388608 + (size_t)grow * 512 + c] = f2bf(v);
                } else { // MODE 5: E = exp(score)
                    ushort_t* C = (ushort_t*)Cv + (size_t)z * (size_t)sC;
                    C[(size_t)grow * (size_t)ldc + gcol] = f2bf(__expf(v));
                }
            }
        }
    }
}

// =====================================================================
// V [8][2048][512] -> Vt [8][512][2048], 64x64 LDS tiles, coalesced both sides
// =====================================================================
__global__ __launch_bounds__(256)
void transpose_v(const ushort_t* __restrict__ V, ushort_t* __restrict__ Vt)
{
    __shared__ ushort_t lds[64][68];
    const int t = threadIdx.x;
    const int nBase = blockIdx.x * 64;
    const int dBase = blockIdx.y * 64;
    const size_t b = blockIdx.z;
    const ushort_t* src = V + b * 1048576;
    ushort_t* dst = Vt + b * 1048576;
#pragma unroll
    for (int i = 0; i < 2; ++i) {
        int s = i * 256 + t;
        int n = s >> 3, dg = s & 7;
        union { ushort_t h[8]; uint4 u; } p;
        p.u = *(const uint4*)(src + (size_t)(nBase + n) * 512 + dBase + dg * 8);
#pragma unroll
        for (int j = 0; j < 8; ++j) lds[n][dg * 8 + j] = p.h[j];
    }
    __syncthreads();
#pragma unroll
    for (int i = 0; i < 2; ++i) {
        int s = i * 256 + t;
        int d = s >> 3, ng = s & 7;
        union { ushort_t h[8]; uint4 u; } p;
#pragma unroll
        for (int j = 0; j < 8; ++j) p.h[j] = lds[ng * 8 + j][d];
        *(uint4*)(dst + (size_t)(dBase + d) * 2048 + nBase + ng * 8) = p.u;
    }
}

// =====================================================================
__global__ __launch_bounds__(256)
void cvt_bf16(const float* __restrict__ src, ushort_t* __restrict__ dst, int n4)
{
    int i = blockIdx.x * 256 + threadIdx.x;
    if (i >= n4) return;
    float4 v = ((const float4*)src)[i];
    union { ushort_t h[4]; uint2 u; } p;
    p.h[0] = f2bf(v.x); p.h[1] = f2bf(v.y); p.h[2] = f2bf(v.z); p.h[3] = f2bf(v.w);
    ((uint2*)dst)[i] = p.u;
}

__global__ __launch_bounds__(256)
void pack_bias(const float* __restrict__ q, const float* __restrict__ k,
               const float* __restrict__ v, float* __restrict__ dst)
{
    int i = blockIdx.x * 256 + threadIdx.x;   // 0..1535
    if (i < 512) dst[i] = q[i];
    else if (i < 1024) dst[i] = k[i - 512];
    else if (i < 1536) dst[i] = v[i - 1024];
}

// =====================================================================
// attn = E/rowsum + intensity, bf16 in-place over E. One block per row.
// =====================================================================
__global__ __launch_bounds__(256)
void norm_add(ushort_t* __restrict__ E, const float* __restrict__ inten)
{
    const int R = blockIdx.x;            // 0..16383
    const int t = threadIdx.x;
    const int w = t >> 6, lane = t & 63;
    ushort_t* erow = E + (size_t)R * 2048;
    const float* irow = inten + (size_t)R * 2048;

    union { ushort_t h[8]; uint4 u; } p;
    p.u = *(const uint4*)(erow + t * 8);
    float f[8];
#pragma unroll
    for (int j = 0; j < 8; ++j) f[j] = bf2f(p.h[j]);

    float s = 0.f;
#pragma unroll
    for (int j = 0; j < 8; ++j) s += f[j];
#pragma unroll
    for (int off = 32; off > 0; off >>= 1) s += __shfl_xor(s, off);

    __shared__ float red[4];
    if (lane == 0) red[w] = s;
    __syncthreads();
    const float inv = 1.f / (red[0] + red[1] + red[2] + red[3]);

    float4 i0 = *(const float4*)(irow + t * 8);
    float4 i1 = *(const float4*)(irow + t * 8 + 4);
    float o[8] = { f[0]*inv + i0.x, f[1]*inv + i0.y, f[2]*inv + i0.z, f[3]*inv + i0.w,
                   f[4]*inv + i1.x, f[5]*inv + i1.y, f[6]*inv + i1.z, f[7]*inv + i1.w };
#pragma unroll
    for (int j = 0; j < 8; ++j) p.h[j] = f2bf(o[j]);
    *(uint4*)(erow + t * 8) = p.u;
}

// =====================================================================
extern "C" void kernel_launch(void* const* d_in, const int* in_sizes, int n_in,
                              void* d_out, int out_size, void* d_ws, size_t ws_size,
                              hipStream_t stream)
{
    const float* X    = (const float*)d_in[0];
    const float* inten= (const float*)d_in[1];
    const float* WQw  = (const float*)d_in[2];
    const float* WQb  = (const float*)d_in[3];
    const float* WKw  = (const float*)d_in[4];
    const float* WKb  = (const float*)d_in[5];
    const float* WVw  = (const float*)d_in[6];
    const float* WVb  = (const float*)d_in[7];
    const float* Wow  = (const float*)d_in[8];
    const float* Wob  = (const float*)d_in[9];
    float* out = (float*)d_out;

    char* ws = (char*)d_ws;
    ushort_t* Xb    = (ushort_t*)(ws + 0);           // 16 MiB (becomes Vt later)
    ushort_t* Wqkv  = (ushort_t*)(ws + 16777216);    // 1536x512 bf16
    ushort_t* Wob2  = (ushort_t*)(ws + 18350080);    // 512x512 bf16
    float*    biasP = (float*)   (ws + 18874368);    // 1536 f32
    ushort_t* QKV   = (ushort_t*)(ws + 19922944);    // Q|K|V row-major, 3x16 MiB
    ushort_t* out1  = (ushort_t*)(ws + 70254592);    // 16 MiB
    ushort_t* Sbf   = (ushort_t*)(ws + 87031808);    // 8x2048x2048 bf16 = 64 MiB
    ushort_t* Qb = QKV;
    ushort_t* Kb = QKV + 8388608;
    ushort_t* Vrm = QKV + 16777216;                  // V row-major
    ushort_t* Vt  = Xb;                              // reuse Xb after proj

    const float scale = 0.044194173824159216f;       // 1/sqrt(512)

    cvt_bf16<<<dim3(8192), dim3(256), 0, stream>>>(X,   Xb, 2097152);
    cvt_bf16<<<dim3(256),  dim3(256), 0, stream>>>(WQw, Wqkv,           65536);
    cvt_bf16<<<dim3(256),  dim3(256), 0, stream>>>(WKw, Wqkv + 262144,  65536);
    cvt_bf16<<<dim3(256),  dim3(256), 0, stream>>>(WVw, Wqkv + 524288,  65536);
    cvt_bf16<<<dim3(256),  dim3(256), 0, stream>>>(Wow, Wob2,           65536);
    pack_bias<<<dim3(6),  dim3(256), 0, stream>>>(WQb, WKb, WVb, biasP);

    // fused QKV projection: [16384,512] @ [1536,512]^T -> Q|K|V row-major
    gemm_nt<4, 128, 32><<<dim3(12, 128, 1), dim3(256), 0, stream>>>(
        Xb, Wqkv, QKV, biasP, 512, 512, 512, 0, 1.f, 0, 0, 0);

    // Vt[b][d][n] = V[b][n][d]  (writes over Xb, which is now dead)
    transpose_v<<<dim3(32, 8, 8), dim3(256), 0, stream>>>(Vrm, Vt);

    // E = exp(scale * Q K^T) bf16, per batch
    gemm_nt<5, 128, 32><<<dim3(16, 16, 8), dim3(256), 0, stream>>>(
        Qb, Kb, Sbf, nullptr, 512, 512, 512, 2048, scale,
        2048LL * 512, 2048LL * 512, 2048LL * 2048);

    // attn = E/rowsum + intensity (bf16, in place)
    norm_add<<<dim3(16384), dim3(256), 0, stream>>>(Sbf, inten);

    // out1 = attn @ Vt^T per batch  [2048,512] bf16
    gemm_nt<0, 64, 32><<<dim3(8, 16, 8), dim3(256), 0, stream>>>(
        Sbf, Vt, out1, nullptr, 2048, 2048, 2048, 512, 1.f,
        2048LL * 2048, 512LL * 2048, 2048LL * 512);

    // out = out1 @ Wo^T + bo  [16384,512] f32
    gemm_nt<3, 64, 32><<<dim3(8, 128, 1), dim3(256), 0, stream>>>(
        out1, Wob2, out, Wob, 512, 512, 512, 512, 1.f, 0, 0, 0);
}